// Round 5
// baseline (173.431 us; speedup 1.0000x reference)
//
#include <hip/hip_runtime.h>
#include <hip/hip_bf16.h>
#include <stdint.h>

typedef __bf16 bf16x8 __attribute__((ext_vector_type(8)));
typedef float  f32x16 __attribute__((ext_vector_type(16)));

#define K2EXP 7.2134752044448170f   /* log2(e)/T */
#define LN2F  0.6931471805599453f

__device__ __forceinline__ unsigned short f2bf(float f) {
  __bf16 h = (__bf16)f;
  return __builtin_bit_cast(unsigned short, h);
}

// ghat: row-normalized g_enc as bf16, pre-swizzled: byte kb of row r lands at
// r*512 + (kb ^ ((r&31)<<4))  -- full 32-slot XOR permutation per 512B row.
__global__ __launch_bounds__(256) void k_ghat(const float* __restrict__ g,
                                              char* __restrict__ ghat) {
  const int w = threadIdx.x >> 6, l = threadIdx.x & 63;
  const int row = blockIdx.x * 4 + w;
  const float4 v = *(const float4*)(g + (size_t)row * 256 + l * 4);
  float s = v.x * v.x + v.y * v.y + v.z * v.z + v.w * v.w;
  #pragma unroll
  for (int m = 1; m <= 32; m <<= 1) s += __shfl_xor(s, m, 64);
  const float rn = rsqrtf(s);
  ushort4 o;
  o.x = f2bf(v.x * rn); o.y = f2bf(v.y * rn);
  o.z = f2bf(v.z * rn); o.w = f2bf(v.w * rn);
  const int off = row * 512 + ((l * 8) ^ ((row & 31) << 4));
  *(ushort4*)(ghat + off) = o;
}

// Main fused kernel. A-panel held in 16 NAMED bf16x8 registers (no ext_vector
// array -> no scratch demotion, rule #20). 8 waves/block, 32 rows/wave,
// B double-buffered through LDS in 32KB chunks, 2 blocks/CU.
__global__ __launch_bounds__(512)
__attribute__((amdgpu_waves_per_eu(4, 4)))
void k_main(const float* __restrict__ l2,
            const char* __restrict__ ghat,
            float* __restrict__ out) {
  __shared__ __align__(16) char smem[2 * 32768 + 1024 + 64];
  float* posl = (float*)(smem + 65536);          // 256 floats
  float* bsum = (float*)(smem + 65536 + 1024);

  const int tid = threadIdx.x;
  const int w   = tid >> 6;      // 0..7
  const int l   = tid & 63;
  const int lm  = l & 31;
  const int lh  = l >> 5;
  const int wrb = blockIdx.x * 256 + w * 32;  // wave's first row
  const int p   = wrb >> 7;                   // positive column (wave-uniform)
  const int pcf = p >> 5;                     // global 32-col fragment of p

  if (tid == 0) *bsum = 0.f;

  auto stage = [&](int c, int buf) {
    const char* gsrc = ghat + c * 32768 + w * 4096 + l * 16;
    char* ldst = smem + buf * 32768 + w * 4096;
    #pragma unroll
    for (int i = 0; i < 4; ++i) {
      __builtin_amdgcn_global_load_lds(
          (const __attribute__((address_space(1))) void*)(gsrc + i * 1024),
          (__attribute__((address_space(3))) void*)(ldst + i * 1024),
          16, 0, 0);
    }
  };

  stage(0, 0);  // fly under the A-load

  // A load + pack + sum-of-squares, single HBM pass. afS: row wrb+lm,
  // k = S*16 + lh*8 .. +8. Named registers -- no array object anywhere.
  bf16x8 af0, af1, af2, af3, af4, af5, af6, af7,
         af8, af9, af10, af11, af12, af13, af14, af15;
  float ssq = 0.f;
  const float* rp = l2 + (size_t)(wrb + lm) * 256 + lh * 8;

#define LOADA(s) { \
    const float4 a = *(const float4*)(rp + (s) * 16); \
    const float4 b = *(const float4*)(rp + (s) * 16 + 4); \
    ssq += a.x*a.x + a.y*a.y + a.z*a.z + a.w*a.w \
         + b.x*b.x + b.y*b.y + b.z*b.z + b.w*b.w; \
    bf16x8 f; \
    f[0] = (__bf16)a.x; f[1] = (__bf16)a.y; f[2] = (__bf16)a.z; f[3] = (__bf16)a.w; \
    f[4] = (__bf16)b.x; f[5] = (__bf16)b.y; f[6] = (__bf16)b.z; f[7] = (__bf16)b.w; \
    af##s = f; }

  LOADA(0) LOADA(1) LOADA(2) LOADA(3)
  __builtin_amdgcn_sched_barrier(0);   // cap in-flight float4s (<128 VGPR)
  LOADA(4) LOADA(5) LOADA(6) LOADA(7)
  __builtin_amdgcn_sched_barrier(0);
  LOADA(8) LOADA(9) LOADA(10) LOADA(11)
  __builtin_amdgcn_sched_barrier(0);
  LOADA(12) LOADA(13) LOADA(14) LOADA(15)
#undef LOADA

  // fold 1/||row|| into af in-register
  const float rn = rsqrtf(ssq + __shfl_xor(ssq, 32, 64));
#define NRM(s) { bf16x8 f = af##s; \
    f[0] = (__bf16)((float)f[0] * rn); f[1] = (__bf16)((float)f[1] * rn); \
    f[2] = (__bf16)((float)f[2] * rn); f[3] = (__bf16)((float)f[3] * rn); \
    f[4] = (__bf16)((float)f[4] * rn); f[5] = (__bf16)((float)f[5] * rn); \
    f[6] = (__bf16)((float)f[6] * rn); f[7] = (__bf16)((float)f[7] * rn); \
    af##s = f; }
  NRM(0) NRM(1) NRM(2) NRM(3) NRM(4) NRM(5) NRM(6) NRM(7)
  NRM(8) NRM(9) NRM(10) NRM(11) NRM(12) NRM(13) NRM(14) NRM(15)
#undef NRM

  float rs0 = 0.f, rs1 = 0.f, rs2 = 0.f, rs3 = 0.f,
        rs4 = 0.f, rs5 = 0.f, rs6 = 0.f, rs7 = 0.f,
        rs8 = 0.f, rs9 = 0.f, rs10 = 0.f, rs11 = 0.f,
        rs12 = 0.f, rs13 = 0.f, rs14 = 0.f, rs15 = 0.f;

  __syncthreads();  // buf0 staged (barrier drains vmcnt) + bsum init visible

#define MSTEP(s) { \
    const uint4 raw = *(const uint4*)(base + col_l * 512 + (((s) * 32 + lh * 16) ^ sw)); \
    acc = __builtin_amdgcn_mfma_f32_32x32x16_bf16( \
              af##s, __builtin_bit_cast(bf16x8, raw), acc, 0, 0, 0); }
#define ESTEP(j) rs##j += __builtin_amdgcn_exp2f(acc[j] * K2EXP);

  for (int c = 0; c < 16; ++c) {
    if (c < 15) stage(c + 1, (c + 1) & 1);   // issue next chunk FIRST
    const char* base = smem + (c & 1) * 32768;
    #pragma unroll
    for (int cf = 0; cf < 2; ++cf) {
      const int col_l = cf * 32 + lm;           // local col in 64-col chunk
      const int sw = (col_l & 31) << 4;
      f32x16 acc = {0.f};
      MSTEP(0)  MSTEP(1)  MSTEP(2)  MSTEP(3)
      MSTEP(4)  MSTEP(5)  MSTEP(6)  MSTEP(7)
      MSTEP(8)  MSTEP(9)  MSTEP(10) MSTEP(11)
      MSTEP(12) MSTEP(13) MSTEP(14) MSTEP(15)
      ESTEP(0)  ESTEP(1)  ESTEP(2)  ESTEP(3)
      ESTEP(4)  ESTEP(5)  ESTEP(6)  ESTEP(7)
      ESTEP(8)  ESTEP(9)  ESTEP(10) ESTEP(11)
      ESTEP(12) ESTEP(13) ESTEP(14) ESTEP(15)
      if (pcf == c * 2 + cf && lm == (p & 31)) {
        #pragma unroll
        for (int j = 0; j < 16; ++j) {
          const int r0 = (j & 3) + 8 * (j >> 2) + 4 * lh;
          posl[w * 32 + r0] = acc[j] * K2EXP;   // log2-scaled positive logit
        }
      }
    }
    __syncthreads();  // chunk c fully read; chunk c+1 staged
  }
#undef MSTEP
#undef ESTEP

  // reduce row sums over the 32 column-lanes of each half-wave
#define RED(j) { float v = rs##j; \
    v += __shfl_xor(v, 1, 64); v += __shfl_xor(v, 2, 64); \
    v += __shfl_xor(v, 4, 64); v += __shfl_xor(v, 8, 64); \
    v += __shfl_xor(v, 16, 64); rs##j = v; }
  RED(0) RED(1) RED(2) RED(3) RED(4) RED(5) RED(6) RED(7)
  RED(8) RED(9) RED(10) RED(11) RED(12) RED(13) RED(14) RED(15)
#undef RED

  if (lm == 0) {  // lanes 0 and 32: 16 rows each
    float local = 0.f;
#define FIN(j) { \
    const int r0 = ((j) & 3) + 8 * ((j) >> 2) + 4 * lh; \
    const float cs = posl[w * 32 + r0]; \
    const float S  = rs##j - __builtin_amdgcn_exp2f(cs); \
    local += (__builtin_amdgcn_logf(S) - cs) * LN2F; }
    FIN(0) FIN(1) FIN(2) FIN(3) FIN(4) FIN(5) FIN(6) FIN(7)
    FIN(8) FIN(9) FIN(10) FIN(11) FIN(12) FIN(13) FIN(14) FIN(15)
#undef FIN
    atomicAdd(bsum, local);
  }
  __syncthreads();
  if (tid == 0) atomicAdd(out, *bsum * (1.0f / 131072.0f));
}

extern "C" void kernel_launch(void* const* d_in, const int* in_sizes, int n_in,
                              void* d_out, int out_size, void* d_ws, size_t ws_size,
                              hipStream_t stream) {
  (void)in_sizes; (void)n_in; (void)out_size; (void)ws_size;
  const float* l2 = (const float*)d_in[0];   // [131072, 256] fp32
  const float* g  = (const float*)d_in[1];   // [1024, 256] fp32
  float* out = (float*)d_out;

  char* ghat = (char*)d_ws;                  // 512 KB bf16, swizzled

  hipMemsetAsync(d_out, 0, sizeof(float), stream);
  k_ghat<<<256, 256, 0, stream>>>(g, ghat);
  k_main<<<512, 512, 0, stream>>>(l2, ghat, out);
}

// Round 6
// 93.439 us; speedup vs baseline: 1.8561x; 1.8561x over previous
//
#include <hip/hip_runtime.h>
#include <hip/hip_bf16.h>
#include <stdint.h>

typedef __bf16 bf16x8 __attribute__((ext_vector_type(8)));
typedef float  f32x16 __attribute__((ext_vector_type(16)));

#define K2EXP 7.2134752044448170f   /* log2(e)/T */
#define LN2F  0.6931471805599453f

__device__ __forceinline__ unsigned short f2bf(float f) {
  __bf16 h = (__bf16)f;
  return __builtin_bit_cast(unsigned short, h);
}

// ghat: row-normalized g_enc as bf16, pre-swizzled: byte kb of row r lands at
// r*512 + (kb ^ ((r&31)<<4))  -- full 32-slot XOR permutation per 512B row.
__global__ __launch_bounds__(256) void k_ghat(const float* __restrict__ g,
                                              char* __restrict__ ghat) {
  const int w = threadIdx.x >> 6, l = threadIdx.x & 63;
  const int row = blockIdx.x * 4 + w;
  const float4 v = *(const float4*)(g + (size_t)row * 256 + l * 4);
  float s = v.x * v.x + v.y * v.y + v.z * v.z + v.w * v.w;
  #pragma unroll
  for (int m = 1; m <= 32; m <<= 1) s += __shfl_xor(s, m, 64);
  const float rn = rsqrtf(s);
  ushort4 o;
  o.x = f2bf(v.x * rn); o.y = f2bf(v.y * rn);
  o.z = f2bf(v.z * rn); o.w = f2bf(v.w * rn);
  const int off = row * 512 + ((l * 8) ^ ((row & 31) << 4));
  *(ushort4*)(ghat + off) = o;
}

// Main fused kernel. 4 waves/block (256 thr), 32 rows/wave, A-panel in 16
// named bf16x8 regs (64 VGPR), B double-buffered through LDS in 32KB chunks.
// Occupancy request: min 2 waves/EU -> 256-reg unified budget (128 arch even
// under a 50/50 arch/AGPR split). LDS 66KB caps at 2 blocks/CU anyway.
__global__ __launch_bounds__(256)
__attribute__((amdgpu_waves_per_eu(2)))
void k_main(const float* __restrict__ l2,
            const char* __restrict__ ghat,
            float* __restrict__ out) {
  __shared__ __align__(16) char smem[2 * 32768 + 512 + 64];
  float* posl = (float*)(smem + 65536);          // 128 floats
  float* bsum = (float*)(smem + 65536 + 512);

  const int tid = threadIdx.x;
  const int w   = tid >> 6;      // 0..3
  const int l   = tid & 63;
  const int lm  = l & 31;
  const int lh  = l >> 5;
  const int wrb = blockIdx.x * 128 + w * 32;  // wave's first row
  const int p   = blockIdx.x;    // positive column (block-uniform: 128 rows/block)
  const int pc  = p >> 6;        // chunk containing p
  const int pf  = (p >> 5) & 1;  // fragment within chunk

  if (tid == 0) *bsum = 0.f;

  // stage one 32KB chunk (64 cols) with 256 threads: 8 x 4KB segments
  auto stage = [&](int c, int buf) {
    const char* gsrc = ghat + c * 32768 + w * 1024 + l * 16;
    char* ldst = smem + buf * 32768 + w * 1024;
    #pragma unroll
    for (int i = 0; i < 8; ++i) {
      __builtin_amdgcn_global_load_lds(
          (const __attribute__((address_space(1))) void*)(gsrc + i * 4096),
          (__attribute__((address_space(3))) void*)(ldst + i * 4096),
          16, 0, 0);
    }
  };

  stage(0, 0);  // fly under the A-load

  // A load + pack + sum-of-squares, single HBM pass. afS: row wrb+lm,
  // k = S*16 + lh*8 .. +8. Named registers.
  bf16x8 af0, af1, af2, af3, af4, af5, af6, af7,
         af8, af9, af10, af11, af12, af13, af14, af15;
  float ssq = 0.f;
  const float* rp = l2 + (size_t)(wrb + lm) * 256 + lh * 8;

#define LOADA(s) { \
    const float4 a = *(const float4*)(rp + (s) * 16); \
    const float4 b = *(const float4*)(rp + (s) * 16 + 4); \
    ssq += a.x*a.x + a.y*a.y + a.z*a.z + a.w*a.w \
         + b.x*b.x + b.y*b.y + b.z*b.z + b.w*b.w; \
    bf16x8 f; \
    f[0] = (__bf16)a.x; f[1] = (__bf16)a.y; f[2] = (__bf16)a.z; f[3] = (__bf16)a.w; \
    f[4] = (__bf16)b.x; f[5] = (__bf16)b.y; f[6] = (__bf16)b.z; f[7] = (__bf16)b.w; \
    af##s = f; }

  LOADA(0) LOADA(1) LOADA(2) LOADA(3)
  __builtin_amdgcn_sched_barrier(0);   // cap in-flight float4s
  LOADA(4) LOADA(5) LOADA(6) LOADA(7)
  __builtin_amdgcn_sched_barrier(0);
  LOADA(8) LOADA(9) LOADA(10) LOADA(11)
  __builtin_amdgcn_sched_barrier(0);
  LOADA(12) LOADA(13) LOADA(14) LOADA(15)
#undef LOADA

  // fold 1/||row|| into af in-register
  const float rn = rsqrtf(ssq + __shfl_xor(ssq, 32, 64));
#define NRM(s) { bf16x8 f = af##s; \
    f[0] = (__bf16)((float)f[0] * rn); f[1] = (__bf16)((float)f[1] * rn); \
    f[2] = (__bf16)((float)f[2] * rn); f[3] = (__bf16)((float)f[3] * rn); \
    f[4] = (__bf16)((float)f[4] * rn); f[5] = (__bf16)((float)f[5] * rn); \
    f[6] = (__bf16)((float)f[6] * rn); f[7] = (__bf16)((float)f[7] * rn); \
    af##s = f; }
  NRM(0) NRM(1) NRM(2) NRM(3) NRM(4) NRM(5) NRM(6) NRM(7)
  NRM(8) NRM(9) NRM(10) NRM(11) NRM(12) NRM(13) NRM(14) NRM(15)
#undef NRM

  float rs0 = 0.f, rs1 = 0.f, rs2 = 0.f, rs3 = 0.f,
        rs4 = 0.f, rs5 = 0.f, rs6 = 0.f, rs7 = 0.f,
        rs8 = 0.f, rs9 = 0.f, rs10 = 0.f, rs11 = 0.f,
        rs12 = 0.f, rs13 = 0.f, rs14 = 0.f, rs15 = 0.f;

  __syncthreads();  // buf0 staged (barrier drains vmcnt) + bsum init visible

#define MSTEP(s) { \
    const uint4 raw = *(const uint4*)(base + col_l * 512 + (((s) * 32 + lh * 16) ^ sw)); \
    acc = __builtin_amdgcn_mfma_f32_32x32x16_bf16( \
              af##s, __builtin_bit_cast(bf16x8, raw), acc, 0, 0, 0); }
#define ESTEP(j) rs##j += __builtin_amdgcn_exp2f(acc[j] * K2EXP);

  for (int c = 0; c < 16; ++c) {
    if (c < 15) stage(c + 1, (c + 1) & 1);   // issue next chunk FIRST
    const char* base = smem + (c & 1) * 32768;
    #pragma unroll
    for (int cf = 0; cf < 2; ++cf) {
      const int col_l = cf * 32 + lm;           // local col in 64-col chunk
      const int sw = (col_l & 31) << 4;
      f32x16 acc = {0.f};
      MSTEP(0)  MSTEP(1)  MSTEP(2)  MSTEP(3)
      MSTEP(4)  MSTEP(5)  MSTEP(6)  MSTEP(7)
      MSTEP(8)  MSTEP(9)  MSTEP(10) MSTEP(11)
      MSTEP(12) MSTEP(13) MSTEP(14) MSTEP(15)
      ESTEP(0)  ESTEP(1)  ESTEP(2)  ESTEP(3)
      ESTEP(4)  ESTEP(5)  ESTEP(6)  ESTEP(7)
      ESTEP(8)  ESTEP(9)  ESTEP(10) ESTEP(11)
      ESTEP(12) ESTEP(13) ESTEP(14) ESTEP(15)
      if (c == pc && cf == pf && lm == (p & 31)) {
        #pragma unroll
        for (int j = 0; j < 16; ++j) {
          const int r0 = (j & 3) + 8 * (j >> 2) + 4 * lh;
          posl[w * 32 + r0] = acc[j] * K2EXP;   // log2-scaled positive logit
        }
      }
    }
    __syncthreads();  // chunk c fully read; chunk c+1 staged
  }
#undef MSTEP
#undef ESTEP

  // reduce row sums over the 32 column-lanes of each half-wave
#define RED(j) { float v = rs##j; \
    v += __shfl_xor(v, 1, 64); v += __shfl_xor(v, 2, 64); \
    v += __shfl_xor(v, 4, 64); v += __shfl_xor(v, 8, 64); \
    v += __shfl_xor(v, 16, 64); rs##j = v; }
  RED(0) RED(1) RED(2) RED(3) RED(4) RED(5) RED(6) RED(7)
  RED(8) RED(9) RED(10) RED(11) RED(12) RED(13) RED(14) RED(15)
#undef RED

  if (lm == 0) {  // lanes 0 and 32: 16 rows each
    float local = 0.f;
#define FIN(j) { \
    const int r0 = ((j) & 3) + 8 * ((j) >> 2) + 4 * lh; \
    const float cs = posl[w * 32 + r0]; \
    const float S  = rs##j - __builtin_amdgcn_exp2f(cs); \
    local += (__builtin_amdgcn_logf(S) - cs) * LN2F; }
    FIN(0) FIN(1) FIN(2) FIN(3) FIN(4) FIN(5) FIN(6) FIN(7)
    FIN(8) FIN(9) FIN(10) FIN(11) FIN(12) FIN(13) FIN(14) FIN(15)
#undef FIN
    atomicAdd(bsum, local);
  }
  __syncthreads();
  if (tid == 0) atomicAdd(out, *bsum * (1.0f / 131072.0f));
}

extern "C" void kernel_launch(void* const* d_in, const int* in_sizes, int n_in,
                              void* d_out, int out_size, void* d_ws, size_t ws_size,
                              hipStream_t stream) {
  (void)in_sizes; (void)n_in; (void)out_size; (void)ws_size;
  const float* l2 = (const float*)d_in[0];   // [131072, 256] fp32
  const float* g  = (const float*)d_in[1];   // [1024, 256] fp32
  float* out = (float*)d_out;

  char* ghat = (char*)d_ws;                  // 512 KB bf16, swizzled

  hipMemsetAsync(d_out, 0, sizeof(float), stream);
  k_ghat<<<256, 256, 0, stream>>>(g, ghat);
  k_main<<<1024, 256, 0, stream>>>(l2, ghat, out);
}